// Round 5
// baseline (116.495 us; speedup 1.0000x reference)
//
#include <hip/hip_runtime.h>

#define IMG 65536                  // H*W

typedef _Float16 half8  __attribute__((ext_vector_type(8)));
typedef _Float16 half4v __attribute__((ext_vector_type(4)));
typedef _Float16 half2v __attribute__((ext_vector_type(2)));
typedef float    floatx4 __attribute__((ext_vector_type(4)));

__device__ __forceinline__ float sigm(float x){ return 1.0f/(1.0f + __expf(-x)); }
__device__ __forceinline__ float tanh_fast(float x){
    float t = __expf(2.0f*x);
    return 1.0f - 2.0f/(t + 1.0f);
}

__global__ void zero_out(float* out){ out[0] = 0.0f; }

__device__ __forceinline__ void row6(const float* __restrict__ u, int rb, int j0, float v[6]){
    const float4 c4 = *(const float4*)&u[rb + j0];
    v[1] = c4.x; v[2] = c4.y; v[3] = c4.z; v[4] = c4.w;
    v[0] = (j0 > 0)   ? u[rb + j0 - 1] : 0.0f;
    v[5] = (j0 < 252) ? u[rb + j0 + 4] : 0.0f;
}
__device__ __forceinline__ void zero6(float v[6]){ v[0]=v[1]=v[2]=v[3]=v[4]=v[5]=0.0f; }

__device__ __forceinline__ void stencil4(const float k2[4], const float m1[4],
    const float m2[4], const float hx[4], const float hs[4], const float hy[4],
    const float vc[6], const float vn[6], const float vs[6], float rp[4])
{
    #pragma unroll
    for (int p = 0; p < 4; ++p){
        float hxx = hx[p], hyy = hy[p];
        rp[p] = (k2[p] + 2.0f*(hxx + hyy))*vc[p+1]
              + (0.5f*m1[p] - hxx)*vc[p+2]
              - (0.5f*m1[p] + hxx)*vc[p]
              + (0.5f*m2[p] - hyy)*vn[p+1]
              - (0.5f*m2[p] + hyy)*vs[p+1]
              - 0.25f*hs[p]*(vn[p+2] - vs[p+2] - vn[p] + vs[p]);
    }
}

// ---------------------------------------------------------------------------
// K1: conv 3x3 (8ch->64oc) MFMA, all 64 oc per block, 4-row strips.
// oc reordered as oc' = t*8+f so the 8 fields of (px,t) sit in one lane pair
// (quad even: f0..3, quad odd: f4..7). Fields stored AoS: fl[bt][row][px][8]
// f16: 0 k2, 1 m1, 2 m2, 3 Hxx, 4 Hs, 5 Hyy, 6 D, 7 pad.
// grid (64 strips, 4 b), 512 threads, LDS 24.8 KB.
// ---------------------------------------------------------------------------
__global__ __launch_bounds__(512) void conv_fields(
    const float* __restrict__ x, const float* __restrict__ w,
    _Float16* __restrict__ fl, float* __restrict__ out)
{
    __shared__ _Float16 xt[6*258*8];     // rows i0-1..i0+4, cols -1..256, 8ch
    __shared__ float red[8];

    const int tid  = threadIdx.x;
    const int lane = tid & 63;
    const int wv   = tid >> 6;
    const int l16  = lane & 15;
    const int quad = lane >> 4;
    const int i0   = blockIdx.x << 2;
    const int b    = blockIdx.y;

    // ---- stage x (f32->f16, ch-pair in low lane bits: conflict-free) ----
    {
        const int cp  = tid & 3;
        const int ccb = tid >> 2;            // 0..127
        const int pl  = ((b << 3) + (cp << 1)) << 16;
        #pragma unroll
        for (int rr = 0; rr < 6; ++rr){
            const int gi = i0 - 1 + rr;
            const bool rowok = (unsigned)gi < 256u;
            const int rowb = pl + (gi << 8);
            #pragma unroll
            for (int p = 0; p < 2; ++p){
                int cc = ccb + (p << 7);
                int gj = cc - 1;
                float v0 = 0.0f, v1 = 0.0f;
                if (rowok && (unsigned)gj < 256u){
                    v0 = x[rowb + gj];
                    v1 = x[rowb + gj + IMG];
                }
                half2v h; h[0] = (_Float16)v0; h[1] = (_Float16)v1;
                *(half2v*)&xt[(rr*258 + cc)*8 + (cp << 1)] = h;
            }
            if (tid < 8){
                int cc = 256 + (tid >> 2);
                int gj = cc - 1;
                float v0 = 0.0f, v1 = 0.0f;
                if (rowok && gj < 256){
                    v0 = x[rowb + gj];
                    v1 = x[rowb + gj + IMG];
                }
                half2v h; h[0] = (_Float16)v0; h[1] = (_Float16)v1;
                *(half2v*)&xt[(rr*258 + cc)*8 + (cp << 1)] = h;
            }
        }
    }

    // ---- weight A-frags for 4 m-groups: A[m=l16][k=quad*8+j] ----
    // oc' = g*16 + l16 = t*8 + f  ->  original oc = f*8 + t
    half8 afr[4][3];
    int boff[3];
    #pragma unroll
    for (int s = 0; s < 3; ++s){
        const int tap = s*4 + quad;
        const int tc  = (tap < 9) ? tap : 8;
        const int dh  = tc/3, dw = tc - dh*3;
        boff[s] = (dh*258 + dw)*8;
        #pragma unroll
        for (int g = 0; g < 4; ++g){
            const int ocp = g*16 + l16;
            const int oc  = ((ocp & 7) << 3) + (ocp >> 3);
            half8 a;
            if (tap < 9){
                #pragma unroll
                for (int j = 0; j < 8; ++j)
                    a[j] = (_Float16)w[(oc*8 + j)*9 + tap];
            } else {
                #pragma unroll
                for (int j = 0; j < 8; ++j) a[j] = (_Float16)0.0f;
            }
            afr[g][s] = a;
        }
    }
    __syncthreads();

    // ---- 64 px-tiles (4 rows x 16 colgroups), 8 per wave ----
    float ldacc = 0.0f;
    const int thalf = quad >> 1;
    const bool flo  = (quad & 1) == 0;
    #pragma unroll 2
    for (int it = 0; it < 8; ++it){
        const int tile = it*8 + wv;
        const int r    = tile >> 4;
        const int jb   = ((tile & 15) << 4) + l16;
        const int base = (r*258 + jb)*8;
        floatx4 acc[4] = {{0,0,0,0},{0,0,0,0},{0,0,0,0},{0,0,0,0}};
        #pragma unroll
        for (int s = 0; s < 3; ++s){
            half8 bf = *(const half8*)&xt[base + boff[s]];
            acc[0] = __builtin_amdgcn_mfma_f32_16x16x32_f16(afr[0][s], bf, acc[0], 0, 0, 0);
            acc[1] = __builtin_amdgcn_mfma_f32_16x16x32_f16(afr[1][s], bf, acc[1], 0, 0, 0);
            acc[2] = __builtin_amdgcn_mfma_f32_16x16x32_f16(afr[2][s], bf, acc[2], 0, 0, 0);
            acc[3] = __builtin_amdgcn_mfma_f32_16x16x32_f16(afr[3][s], bf, acc[3], 0, 0, 0);
        }
        const int gi = i0 + r;
        #pragma unroll
        for (int g = 0; g < 4; ++g){
            const int t   = g*2 + thalf;       // lane's t for this acc
            const int pix = ((((b << 3) + t) << 8) + gi << 8) + jb;
            half4v v;
            if (flo){                          // f0..3: k2, m1, m2, Hxx
                float s0 = 0.99f*sigm(acc[g][0]) + 0.01f;
                v[0] = (_Float16)(s0*s0);
                v[1] = (_Float16)acc[g][1];
                v[2] = (_Float16)acc[g][2];
                v[3] = (_Float16)(0.99f*sigm(acc[g][3]) + 0.01f);
                *(half4v*)&fl[(pix << 3)] = v;
            } else {                           // f4..7: Hxy,Hyx,Hyy,tau
                float hs  = 0.1f*(tanh_fast(acc[g][0]) + tanh_fast(acc[g][1]));
                float hyy = 0.99f*sigm(acc[g][2]) + 0.01f;
                float tau = 9.9f*sigm(acc[g][3]) + 0.1f;
                v[0] = (_Float16)hs;
                v[1] = (_Float16)hyy;
                v[2] = (_Float16)(1.0f/(tau*tau));
                v[3] = (_Float16)0.0f;
                *(half4v*)&fl[(pix << 3) + 4] = v;
                ldacc += __logf(tau);          // -0.5*logdetD == +sum log tau
            }
        }
    }

    // ---- logdet reduction ----
    float v = ldacc;
    #pragma unroll
    for (int off = 1; off < 64; off <<= 1) v += __shfl_xor(v, off, 64);
    if (lane == 0) red[wv] = v;
    __syncthreads();
    if (tid == 0){
        float s = 0.0f;
        #pragma unroll
        for (int k = 0; k < 8; ++k) s += red[k];
        atomicAdd(out, s);
    }
}

// ---------------------------------------------------------------------------
// K2: z = A(A(x)); r = x + z - x_prev; out += 0.5*sum(D r^2).
// Block = (bt, 8-row strip), 256 threads, y in LDS (10 rows). Fields read
// as one b128 AoS load per px. grid (32, 32) = 1024 blocks.
// ---------------------------------------------------------------------------
__global__ __launch_bounds__(256) void fused_AA(
    const float* __restrict__ x, const _Float16* __restrict__ fl,
    float* __restrict__ out)
{
    __shared__ float ys[10*268];
    __shared__ float red[4];

    const int tid = threadIdx.x;
    const int bt  = blockIdx.y;
    const int t   = bt & 7;
    const int i0  = blockIdx.x << 3;

    if (tid < 20) ys[(tid >> 1)*268 + ((tid & 1) ? 260 : 3)] = 0.0f;

    // ---- Y: y = A(x), rows i0-1 .. i0+8 (640 tasks) ----
    #pragma unroll
    for (int p = 0; p < 3; ++p){
        if (p == 2 && tid >= 128) break;
        const int task = p*256 + tid;
        const int ry = task >> 6;
        const int jc = (task & 63) << 2;
        const int gi = i0 - 1 + ry;
        float4 y4 = make_float4(0,0,0,0);
        if ((unsigned)gi < 256u){
            const int pix = (bt << 16) + (gi << 8) + jc;
            const int rb  = pix - jc;
            float vc[6], vn[6], vs[6];
            row6(x, rb, jc, vc);
            if (gi < 255) row6(x, rb + 256, jc, vn); else zero6(vn);
            if (gi > 0)   row6(x, rb - 256, jc, vs); else zero6(vs);
            float k2[4], m1[4], m2[4], hx[4], hsv[4], hy[4], yv[4];
            #pragma unroll
            for (int q = 0; q < 4; ++q){
                half8 f8 = *(const half8*)&fl[(pix + q) << 3];
                k2[q]=(float)f8[0]; m1[q]=(float)f8[1]; m2[q]=(float)f8[2];
                hx[q]=(float)f8[3]; hsv[q]=(float)f8[4]; hy[q]=(float)f8[5];
            }
            stencil4(k2, m1, m2, hx, hsv, hy, vc, vn, vs, yv);
            y4 = make_float4(yv[0], yv[1], yv[2], yv[3]);
        }
        *(float4*)&ys[ry*268 + 4 + jc] = y4;
    }
    __syncthreads();

    // ---- Z: z = A(y), rows i0..i0+7 (512 tasks); residual + reduce ----
    float local = 0.0f;
    #pragma unroll
    for (int p = 0; p < 2; ++p){
        const int task = p*256 + tid;
        const int zr = task >> 6;
        const int jc = (task & 63) << 2;
        const int gi = i0 + zr;
        const int pix = (bt << 16) + (gi << 8) + jc;
        const int yb  = (zr + 1)*268 + 4 + jc;

        float vc[6], vn[6], vs[6];
        {
            float4 c4 = *(const float4*)&ys[yb];
            vc[1]=c4.x; vc[2]=c4.y; vc[3]=c4.z; vc[4]=c4.w;
            vc[0]=ys[yb-1]; vc[5]=ys[yb+4];
            float4 n4 = *(const float4*)&ys[yb+268];
            vn[1]=n4.x; vn[2]=n4.y; vn[3]=n4.z; vn[4]=n4.w;
            vn[0]=ys[yb+268-1]; vn[5]=ys[yb+268+4];
            float4 s4 = *(const float4*)&ys[yb-268];
            vs[1]=s4.x; vs[2]=s4.y; vs[3]=s4.z; vs[4]=s4.w;
            vs[0]=ys[yb-268-1]; vs[5]=ys[yb-268+4];
        }
        float k2[4], m1[4], m2[4], hx[4], hsv[4], hy[4], dv[4], zv[4];
        #pragma unroll
        for (int q = 0; q < 4; ++q){
            half8 f8 = *(const half8*)&fl[(pix + q) << 3];
            k2[q]=(float)f8[0]; m1[q]=(float)f8[1]; m2[q]=(float)f8[2];
            hx[q]=(float)f8[3]; hsv[q]=(float)f8[4]; hy[q]=(float)f8[5];
            dv[q]=(float)f8[6];
        }
        stencil4(k2, m1, m2, hx, hsv, hy, vc, vn, vs, zv);

        float4 xc = *(const float4*)&x[pix];
        float4 xp = make_float4(0,0,0,0);
        if (t > 0) xp = *(const float4*)&x[pix - IMG];
        const float* xcp = (const float*)&xc;
        const float* xpp = (const float*)&xp;
        #pragma unroll
        for (int q = 0; q < 4; ++q){
            float r = xcp[q] + zv[q] - xpp[q];
            local += dv[q]*r*r;
        }
    }

    float v = local;
    #pragma unroll
    for (int off = 1; off < 64; off <<= 1) v += __shfl_xor(v, off, 64);
    if ((tid & 63) == 0) red[tid >> 6] = v;
    __syncthreads();
    if (tid == 0)
        atomicAdd(out, 0.5f*(red[0] + red[1] + red[2] + red[3]));
}

extern "C" void kernel_launch(void* const* d_in, const int* in_sizes, int n_in,
                              void* d_out, int out_size, void* d_ws, size_t ws_size,
                              hipStream_t stream)
{
    const float* x = (const float*)d_in[0];
    const float* w = (const float*)d_in[1];
    float* out = (float*)d_out;
    _Float16* fl = (_Float16*)d_ws;

    zero_out<<<1, 1, 0, stream>>>(out);
    conv_fields<<<dim3(64, 4), 512, 0, stream>>>(x, w, fl, out);
    fused_AA<<<dim3(32, 32), 256, 0, stream>>>(x, fl, out);
}

// Round 6
// 110.212 us; speedup vs baseline: 1.0570x; 1.0570x over previous
//
#include <hip/hip_runtime.h>

#define IMG 65536                  // H*W

typedef _Float16 half8  __attribute__((ext_vector_type(8)));
typedef _Float16 half4v __attribute__((ext_vector_type(4)));
typedef _Float16 half2v __attribute__((ext_vector_type(2)));
typedef float    floatx4 __attribute__((ext_vector_type(4)));

__device__ __forceinline__ float sigm(float x){ return 1.0f/(1.0f + __expf(-x)); }
__device__ __forceinline__ float tanh_fast(float x){
    float t = __expf(2.0f*x);
    return 1.0f - 2.0f/(t + 1.0f);
}

__global__ void zero_out(float* out){ out[0] = 0.0f; }

__device__ __forceinline__ void row6(const float* __restrict__ u, int rb, int j0, float v[6]){
    const float4 c4 = *(const float4*)&u[rb + j0];
    v[1] = c4.x; v[2] = c4.y; v[3] = c4.z; v[4] = c4.w;
    v[0] = (j0 > 0)   ? u[rb + j0 - 1] : 0.0f;
    v[5] = (j0 < 252) ? u[rb + j0 + 4] : 0.0f;
}
__device__ __forceinline__ void zero6(float v[6]){ v[0]=v[1]=v[2]=v[3]=v[4]=v[5]=0.0f; }

__device__ __forceinline__ void stencil4(const float k2[4], const float m1[4],
    const float m2[4], const float hx[4], const float hs[4], const float hy[4],
    const float vc[6], const float vn[6], const float vs[6], float rp[4])
{
    #pragma unroll
    for (int p = 0; p < 4; ++p){
        float hxx = hx[p], hyy = hy[p];
        rp[p] = (k2[p] + 2.0f*(hxx + hyy))*vc[p+1]
              + (0.5f*m1[p] - hxx)*vc[p+2]
              - (0.5f*m1[p] + hxx)*vc[p]
              + (0.5f*m2[p] - hyy)*vn[p+1]
              - (0.5f*m2[p] + hyy)*vs[p+1]
              - 0.25f*hs[p]*(vn[p+2] - vs[p+2] - vn[p] + vs[p]);
    }
}

// ---------------------------------------------------------------------------
// K1: conv 3x3 (8ch->64oc) MFMA, all 64 oc per block, 2-row strips.
// Weights LDS-staged (coalesced once, ds_read_b128 frags). oc' = t*8+f so the
// 8 fields of (px,t) sit in a lane pair. Fields AoS: fl[bt][row][px][8] f16:
// 0 k2, 1 m1, 2 m2, 3 Hxx, 4 Hs, 5 Hyy, 6 D, 7 pad.
// grid (128 strips, 4 b), 512 threads, LDS 45.4 KB -> 2 blocks/CU.
// ---------------------------------------------------------------------------
__global__ __launch_bounds__(512, 4) void conv_fields(
    const float* __restrict__ x, const float* __restrict__ w,
    _Float16* __restrict__ fl, float* __restrict__ out)
{
    __shared__ _Float16 xt[4*258*8];     // rows i0-1..i0+2, cols -1..256, 8ch
    __shared__ _Float16 Wl[12*64*8];     // [tap][ocp][c], taps 9..11 zero
    __shared__ float red[8];

    const int tid  = threadIdx.x;
    const int lane = tid & 63;
    const int wv   = tid >> 6;
    const int l16  = lane & 15;
    const int quad = lane >> 4;
    const int i0   = blockIdx.x << 1;    // field rows i0, i0+1
    const int b    = blockIdx.y;

    // ---- stage weights to LDS: Wl[(tap*64+ocp)*8+c], ocp=t*8+f, oc=f*8+t ----
    for (int e = tid; e < 12*64*8; e += 512){
        const int c   = e & 7;
        const int ocp = (e >> 3) & 63;
        const int tap = e >> 9;
        const int oc  = ((ocp & 7) << 3) + (ocp >> 3);
        Wl[e] = (_Float16)((tap < 9) ? w[(oc*8 + c)*9 + tap] : 0.0f);
    }

    // ---- stage x rows i0-1..i0+2 (f32->f16, ch-pair in low lane bits) ----
    {
        const int cp  = tid & 3;
        const int ccb = tid >> 2;            // 0..127
        const int pl  = ((b << 3) + (cp << 1)) << 16;
        #pragma unroll
        for (int rr = 0; rr < 4; ++rr){
            const int gi = i0 - 1 + rr;
            const bool rowok = (unsigned)gi < 256u;
            const int rowb = pl + (gi << 8);
            #pragma unroll
            for (int p = 0; p < 2; ++p){
                int cc = ccb + (p << 7);
                int gj = cc - 1;
                float v0 = 0.0f, v1 = 0.0f;
                if (rowok && (unsigned)gj < 256u){
                    v0 = x[rowb + gj];
                    v1 = x[rowb + gj + IMG];
                }
                half2v h; h[0] = (_Float16)v0; h[1] = (_Float16)v1;
                *(half2v*)&xt[(rr*258 + cc)*8 + (cp << 1)] = h;
            }
            if (tid < 8){
                int cc = 256 + (tid >> 2);
                int gj = cc - 1;
                float v0 = 0.0f, v1 = 0.0f;
                if (rowok && gj < 256){
                    v0 = x[rowb + gj];
                    v1 = x[rowb + gj + IMG];
                }
                half2v h; h[0] = (_Float16)v0; h[1] = (_Float16)v1;
                *(half2v*)&xt[(rr*258 + cc)*8 + (cp << 1)] = h;
            }
        }
    }
    __syncthreads();

    // ---- A-frags from LDS: afr[g][s] = Wl[tap=s*4+quad][ocp=g*16+l16][:] ----
    half8 afr[4][3];
    int boff[3];
    #pragma unroll
    for (int s = 0; s < 3; ++s){
        const int tap = s*4 + quad;
        const int tc  = (tap < 9) ? tap : 8;
        const int dh  = tc/3, dw = tc - dh*3;
        boff[s] = (dh*258 + dw)*8;
        #pragma unroll
        for (int g = 0; g < 4; ++g)
            afr[g][s] = *(const half8*)&Wl[(tap*64 + g*16 + l16)*8];
    }

    // ---- 32 px-tiles (2 rows x 16 colgroups), 4 per wave ----
    float ldacc = 0.0f;
    const int thalf = quad >> 1;
    const bool flo  = (quad & 1) == 0;
    #pragma unroll
    for (int it = 0; it < 4; ++it){
        const int tile = it*8 + wv;
        const int r    = tile >> 4;
        const int jb   = ((tile & 15) << 4) + l16;
        const int base = (r*258 + jb)*8;
        floatx4 acc[4] = {{0,0,0,0},{0,0,0,0},{0,0,0,0},{0,0,0,0}};
        #pragma unroll
        for (int s = 0; s < 3; ++s){
            half8 bf = *(const half8*)&xt[base + boff[s]];
            acc[0] = __builtin_amdgcn_mfma_f32_16x16x32_f16(afr[0][s], bf, acc[0], 0, 0, 0);
            acc[1] = __builtin_amdgcn_mfma_f32_16x16x32_f16(afr[1][s], bf, acc[1], 0, 0, 0);
            acc[2] = __builtin_amdgcn_mfma_f32_16x16x32_f16(afr[2][s], bf, acc[2], 0, 0, 0);
            acc[3] = __builtin_amdgcn_mfma_f32_16x16x32_f16(afr[3][s], bf, acc[3], 0, 0, 0);
        }
        const int gi = i0 + r;
        #pragma unroll
        for (int g = 0; g < 4; ++g){
            const int t   = g*2 + thalf;
            const int pix = ((((b << 3) + t) << 8) + gi << 8) + jb;
            half4v v;
            if (flo){                          // f0..3: k2, m1, m2, Hxx
                float s0 = 0.99f*sigm(acc[g][0]) + 0.01f;
                v[0] = (_Float16)(s0*s0);
                v[1] = (_Float16)acc[g][1];
                v[2] = (_Float16)acc[g][2];
                v[3] = (_Float16)(0.99f*sigm(acc[g][3]) + 0.01f);
                *(half4v*)&fl[(pix << 3)] = v;
            } else {                           // f4..7: Hxy,Hyx,Hyy,tau
                float hs  = 0.1f*(tanh_fast(acc[g][0]) + tanh_fast(acc[g][1]));
                float hyy = 0.99f*sigm(acc[g][2]) + 0.01f;
                float tau = 9.9f*sigm(acc[g][3]) + 0.1f;
                v[0] = (_Float16)hs;
                v[1] = (_Float16)hyy;
                v[2] = (_Float16)(1.0f/(tau*tau));
                v[3] = (_Float16)0.0f;
                *(half4v*)&fl[(pix << 3) + 4] = v;
                ldacc += __logf(tau);          // -0.5*logdetD == +sum log tau
            }
        }
    }

    // ---- logdet reduction ----
    float v = ldacc;
    #pragma unroll
    for (int off = 1; off < 64; off <<= 1) v += __shfl_xor(v, off, 64);
    if (lane == 0) red[wv] = v;
    __syncthreads();
    if (tid == 0){
        float s = 0.0f;
        #pragma unroll
        for (int k = 0; k < 8; ++k) s += red[k];
        atomicAdd(out, s);
    }
}

// ---------------------------------------------------------------------------
// K2: z = A(A(x)); r = x + z - x_prev; out += 0.5*sum(D r^2).
// Block = (bt, 8-row strip), 256 threads, y in LDS (10 rows). Fields read
// as one b128 AoS load per px. grid (32, 32) = 1024 blocks.
// ---------------------------------------------------------------------------
__global__ __launch_bounds__(256) void fused_AA(
    const float* __restrict__ x, const _Float16* __restrict__ fl,
    float* __restrict__ out)
{
    __shared__ float ys[10*268];
    __shared__ float red[4];

    const int tid = threadIdx.x;
    const int bt  = blockIdx.y;
    const int t   = bt & 7;
    const int i0  = blockIdx.x << 3;

    if (tid < 20) ys[(tid >> 1)*268 + ((tid & 1) ? 260 : 3)] = 0.0f;

    // ---- Y: y = A(x), rows i0-1 .. i0+8 (640 tasks) ----
    #pragma unroll
    for (int p = 0; p < 3; ++p){
        if (p == 2 && tid >= 128) break;
        const int task = p*256 + tid;
        const int ry = task >> 6;
        const int jc = (task & 63) << 2;
        const int gi = i0 - 1 + ry;
        float4 y4 = make_float4(0,0,0,0);
        if ((unsigned)gi < 256u){
            const int pix = (bt << 16) + (gi << 8) + jc;
            const int rb  = pix - jc;
            float vc[6], vn[6], vs[6];
            row6(x, rb, jc, vc);
            if (gi < 255) row6(x, rb + 256, jc, vn); else zero6(vn);
            if (gi > 0)   row6(x, rb - 256, jc, vs); else zero6(vs);
            float k2[4], m1[4], m2[4], hx[4], hsv[4], hy[4], yv[4];
            #pragma unroll
            for (int q = 0; q < 4; ++q){
                half8 f8 = *(const half8*)&fl[(pix + q) << 3];
                k2[q]=(float)f8[0]; m1[q]=(float)f8[1]; m2[q]=(float)f8[2];
                hx[q]=(float)f8[3]; hsv[q]=(float)f8[4]; hy[q]=(float)f8[5];
            }
            stencil4(k2, m1, m2, hx, hsv, hy, vc, vn, vs, yv);
            y4 = make_float4(yv[0], yv[1], yv[2], yv[3]);
        }
        *(float4*)&ys[ry*268 + 4 + jc] = y4;
    }
    __syncthreads();

    // ---- Z: z = A(y), rows i0..i0+7 (512 tasks); residual + reduce ----
    float local = 0.0f;
    #pragma unroll
    for (int p = 0; p < 2; ++p){
        const int task = p*256 + tid;
        const int zr = task >> 6;
        const int jc = (task & 63) << 2;
        const int gi = i0 + zr;
        const int pix = (bt << 16) + (gi << 8) + jc;
        const int yb  = (zr + 1)*268 + 4 + jc;

        float vc[6], vn[6], vs[6];
        {
            float4 c4 = *(const float4*)&ys[yb];
            vc[1]=c4.x; vc[2]=c4.y; vc[3]=c4.z; vc[4]=c4.w;
            vc[0]=ys[yb-1]; vc[5]=ys[yb+4];
            float4 n4 = *(const float4*)&ys[yb+268];
            vn[1]=n4.x; vn[2]=n4.y; vn[3]=n4.z; vn[4]=n4.w;
            vn[0]=ys[yb+268-1]; vn[5]=ys[yb+268+4];
            float4 s4 = *(const float4*)&ys[yb-268];
            vs[1]=s4.x; vs[2]=s4.y; vs[3]=s4.z; vs[4]=s4.w;
            vs[0]=ys[yb-268-1]; vs[5]=ys[yb-268+4];
        }
        float k2[4], m1[4], m2[4], hx[4], hsv[4], hy[4], dv[4], zv[4];
        #pragma unroll
        for (int q = 0; q < 4; ++q){
            half8 f8 = *(const half8*)&fl[(pix + q) << 3];
            k2[q]=(float)f8[0]; m1[q]=(float)f8[1]; m2[q]=(float)f8[2];
            hx[q]=(float)f8[3]; hsv[q]=(float)f8[4]; hy[q]=(float)f8[5];
            dv[q]=(float)f8[6];
        }
        stencil4(k2, m1, m2, hx, hsv, hy, vc, vn, vs, zv);

        float4 xc = *(const float4*)&x[pix];
        float4 xp = make_float4(0,0,0,0);
        if (t > 0) xp = *(const float4*)&x[pix - IMG];
        const float* xcp = (const float*)&xc;
        const float* xpp = (const float*)&xp;
        #pragma unroll
        for (int q = 0; q < 4; ++q){
            float r = xcp[q] + zv[q] - xpp[q];
            local += dv[q]*r*r;
        }
    }

    float v = local;
    #pragma unroll
    for (int off = 1; off < 64; off <<= 1) v += __shfl_xor(v, off, 64);
    if ((tid & 63) == 0) red[tid >> 6] = v;
    __syncthreads();
    if (tid == 0)
        atomicAdd(out, 0.5f*(red[0] + red[1] + red[2] + red[3]));
}

extern "C" void kernel_launch(void* const* d_in, const int* in_sizes, int n_in,
                              void* d_out, int out_size, void* d_ws, size_t ws_size,
                              hipStream_t stream)
{
    const float* x = (const float*)d_in[0];
    const float* w = (const float*)d_in[1];
    float* out = (float*)d_out;
    _Float16* fl = (_Float16*)d_ws;

    zero_out<<<1, 1, 0, stream>>>(out);
    conv_fields<<<dim3(128, 4), 512, 0, stream>>>(x, w, fl, out);
    fused_AA<<<dim3(32, 32), 256, 0, stream>>>(x, fl, out);
}